// Round 1
// baseline (176.815 us; speedup 1.0000x reference)
//
#include <hip/hip_runtime.h>

#define NN 1026   // nodes per chain
#define NE 1025   // edges
#define NA 1024   // angles
#define BLK 256

__global__ __launch_bounds__(BLK)
void equil_kernel(const float* __restrict__ pos0,
                  const float* __restrict__ tip_pos,
                  const float* __restrict__ thetas_ss,
                  const int*   __restrict__ buckle,
                  const float* __restrict__ kstiff_p,
                  const float* __restrict__ ksoft_p,
                  const float* __restrict__ kstretch_p,
                  float* __restrict__ out)
{
    __shared__ float px[NN], py[NN], vx[NN], vy[NN];
    __shared__ float ex[NE], ey[NE], il2[NE], sc[NE];
    __shared__ float axs[NA], ays[NA], bxs[NA], bys[NA];
    __shared__ float th[NA], npl[NA];

    const int b   = blockIdx.x;
    const int tid = threadIdx.x;
    const float k_stiff = kstiff_p[0];
    const float k_soft  = ksoft_p[0];
    const float k_str   = kstretch_p[0];

    // ---- init: load chain state into LDS ----
    const float* p0 = pos0 + (size_t)b * NN * 2;
    for (int i = tid; i < NN; i += BLK) {
        px[i] = p0[2*i];
        py[i] = p0[2*i+1];
        vx[i] = 0.f; vy[i] = 0.f;
    }
    for (int j = tid; j < NA; j += BLK) {
        th[j] = thetas_ss[j];
        // n_plus = #(buckle_pm == +1) = sum of buckle bits
        int np_ = buckle[4*j] + buckle[4*j+1] + buckle[4*j+2] + buckle[4*j+3];
        npl[j] = (float)np_;
    }
    if (tid == 0) {  // tip node pinned to tip_pos
        px[NN-1] = tip_pos[2*b];
        py[NN-1] = tip_pos[2*b+1];
    }
    __syncthreads();

    for (int step = 0; step < 64; ++step) {
        // ---- phase A: per-edge quantities ----
        for (int i = tid; i < NE; i += BLK) {
            float dx = px[i+1]-px[i], dy = py[i+1]-py[i];
            float l2 = dx*dx + dy*dy;
            float len = sqrtf(l2);
            ex[i]  = dx; ey[i] = dy;
            il2[i] = 1.0f / l2;
            sc[i]  = k_str * (len - 1.0f) / len;   // S_i = sc*d_i
        }
        __syncthreads();

        // ---- phase B: per-angle bend gradients ----
        for (int j = tid; j < NA; j += BLK) {
            float v1x = ex[j],   v1y = ey[j];
            float v2x = ex[j+1], v2y = ey[j+1];
            float cr = v1x*v2y - v1y*v2x;
            float dt_ = v1x*v2x + v1y*v2y;
            float theta = atan2f(cr, dt_);
            float TH  = th[j];
            float np_ = npl[j];
            float cnt = (theta <  TH ? np_        : 0.f)
                      + (theta > -TH ? 4.f - np_  : 0.f);
            float K = cnt * k_stiff + (4.f - cnt) * k_soft;
            float m = K * (theta - TH);
            float m1 = m * il2[j], m2 = m * il2[j+1];
            // a_j = m * dtheta/dv1 ; b_j = m * dtheta/dv2
            axs[j] =  m1 * v1y;  ays[j] = -m1 * v1x;
            bxs[j] = -m2 * v2y;  bys[j] =  m2 * v2x;
        }
        __syncthreads();

        // ---- phase C+D: gather force, integrate free nodes 2..NN-2 ----
        for (int i = 2 + tid; i <= NN-2; i += BLK) {
            // stretch: f_i = S_i - S_{i-1}
            float fx = sc[i]*ex[i] - sc[i-1]*ex[i-1];
            float fy = sc[i]*ey[i] - sc[i-1]*ey[i-1];
            // bend: f_j += a_j ; f_{j+1} += b_j - a_j ; f_{j+2} -= b_j
            if (i <= NA-1) { fx += axs[i]; fy += ays[i]; }          // j = i
            fx += bxs[i-1] - axs[i-1];  fy += bys[i-1] - ays[i-1];  // j = i-1
            fx -= bxs[i-2];             fy -= bys[i-2];             // j = i-2
            float vx_ = vx[i], vy_ = vy[i];
            vx_ += 0.001f * (fx - 2.0f * vx_);
            vy_ += 0.001f * (fy - 2.0f * vy_);
            vx[i] = vx_; vy[i] = vy_;
            px[i] += 0.001f * vx_;
            py[i] += 0.001f * vy_;
        }
        __syncthreads();
    }

    // ---- epilogue: write final positions ----
    float* o = out + (size_t)b * NN * 2;
    for (int i = tid; i < NN; i += BLK) {
        o[2*i]   = px[i];
        o[2*i+1] = py[i];
    }
}

extern "C" void kernel_launch(void* const* d_in, const int* in_sizes, int n_in,
                              void* d_out, int out_size, void* d_ws, size_t ws_size,
                              hipStream_t stream) {
    const float* pos0   = (const float*)d_in[0];
    const float* tip    = (const float*)d_in[1];
    const float* thetas = (const float*)d_in[2];
    const int*   buckle = (const int*)  d_in[3];
    const float* ks     = (const float*)d_in[4];
    const float* ko     = (const float*)d_in[5];
    const float* kr     = (const float*)d_in[6];
    float* out = (float*)d_out;
    hipLaunchKernelGGL(equil_kernel, dim3(256), dim3(BLK), 0, stream,
                       pos0, tip, thetas, buckle, ks, ko, kr, out);
}

// Round 2
// 83.125 us; speedup vs baseline: 2.1271x; 2.1271x over previous
//
#include <hip/hip_runtime.h>

#define NN 1026   // nodes per chain
#define NE 1025   // edges
#define NA 1024   // angles
#define BLK 1024

__global__ __launch_bounds__(BLK)
void equil_kernel(const float* __restrict__ pos0,
                  const float* __restrict__ tip_pos,
                  const float* __restrict__ thetas_ss,
                  const int*   __restrict__ buckle,
                  const float* __restrict__ kstiff_p,
                  const float* __restrict__ ksoft_p,
                  const float* __restrict__ kstretch_p,
                  float* __restrict__ out)
{
    __shared__ float2 pos[NN];        // node positions
    __shared__ float2 sf[NE];         // stretch force vector per edge
    __shared__ float2 aarr[NA + 1];   // bend grad wrt v1 (zero-padded at NA)
    __shared__ float2 barr[NA + 1];   // bend grad wrt v2 (zero-padded at NA)

    const int b   = blockIdx.x;
    const int tid = threadIdx.x;
    const float k_stiff = kstiff_p[0];
    const float k_soft  = ksoft_p[0];
    const float k_str   = kstretch_p[0];

    // ---- init ----
    const float2* p0 = (const float2*)(pos0 + (size_t)b * NN * 2);
    pos[tid] = p0[tid];                       // nodes 0..1023
    if (tid == 0) pos[NA] = p0[NA];           // node 1024
    if (tid == 1) {                           // node 1025 = tip (pinned)
        float2 t; t.x = tip_pos[2*b]; t.y = tip_pos[2*b+1];
        pos[NN-1] = t;
    }
    if (tid == 2) {
        aarr[NA] = make_float2(0.f, 0.f);
        barr[NA] = make_float2(0.f, 0.f);
    }
    // per-thread constants: angle tid
    const float TH = thetas_ss[tid];
    const int4 bk  = ((const int4*)buckle)[tid];
    const float npl = (float)(bk.x + bk.y + bk.z + bk.w);   // #(pm==+1)
    // velocity + position of owned free node i = tid+2 live in registers
    float vxr = 0.f, vyr = 0.f;
    __syncthreads();
    float2 myp = pos[tid + 2];   // valid for tid<=1022 (node 2..1024)

    for (int s = 0; s < 64; ++s) {
        // ---- phase AB: per-angle bend + per-edge stretch (fused) ----
        float2 pa = pos[tid], pb = pos[tid+1], pc = pos[tid+2];
        float v1x = pb.x - pa.x, v1y = pb.y - pa.y;
        float v2x = pc.x - pb.x, v2y = pc.y - pb.y;
        float cr  = v1x*v2y - v1y*v2x;
        float dt_ = v1x*v2x + v1y*v2y;
        float theta = atan2f(cr, dt_);
        float l2a = v1x*v1x + v1y*v1y;
        float l2b = v2x*v2x + v2y*v2y;
        float cnt = (theta <  TH ? npl       : 0.f)
                  + (theta > -TH ? 4.f - npl : 0.f);
        float K = cnt * k_stiff + (4.f - cnt) * k_soft;
        float m = K * (theta - TH);
        float m1 = m / l2a, m2 = m / l2b;
        float2 av; av.x =  m1 * v1y; av.y = -m1 * v1x;
        float2 bv; bv.x = -m2 * v2y; bv.y =  m2 * v2x;
        aarr[tid] = av;
        barr[tid] = bv;
        float lena = sqrtf(l2a);
        float sca  = k_str * (lena - 1.0f) / lena;
        float2 s1; s1.x = sca * v1x; s1.y = sca * v1y;
        sf[tid] = s1;
        if (tid == NA - 1) {   // last edge (1024) handled by last angle thread
            float lenb = sqrtf(l2b);
            float scb  = k_str * (lenb - 1.0f) / lenb;
            float2 s2; s2.x = scb * v2x; s2.y = scb * v2y;
            sf[NA] = s2;
        }
        __syncthreads();

        // ---- phase C: gather force + integrate free node i = tid+2 ----
        if (tid <= NN - 4) {   // tid<=1022, free nodes 2..1024
            const int i = tid + 2;
            float2 sfi  = sf[i], sfim = sf[i-1];
            float2 ai   = aarr[i];      // zero at i==1024 via pad
            float2 aim  = aarr[i-1];
            float2 bim  = barr[i-1];
            float2 bim2 = barr[i-2];
            float fx = sfi.x - sfim.x + ai.x + (bim.x - aim.x) - bim2.x;
            float fy = sfi.y - sfim.y + ai.y + (bim.y - aim.y) - bim2.y;
            vxr += 0.001f * (fx - 2.0f * vxr);
            vyr += 0.001f * (fy - 2.0f * vyr);
            myp.x += 0.001f * vxr;
            myp.y += 0.001f * vyr;
            pos[i] = myp;
        }
        __syncthreads();
    }

    // ---- epilogue ----
    float2* o = (float2*)(out + (size_t)b * NN * 2);
    o[tid] = pos[tid];
    if (tid < 2) o[NA + tid] = pos[NA + tid];
}

extern "C" void kernel_launch(void* const* d_in, const int* in_sizes, int n_in,
                              void* d_out, int out_size, void* d_ws, size_t ws_size,
                              hipStream_t stream) {
    const float* pos0   = (const float*)d_in[0];
    const float* tip    = (const float*)d_in[1];
    const float* thetas = (const float*)d_in[2];
    const int*   buckle = (const int*)  d_in[3];
    const float* ks     = (const float*)d_in[4];
    const float* ko     = (const float*)d_in[5];
    const float* kr     = (const float*)d_in[6];
    float* out = (float*)d_out;
    hipLaunchKernelGGL(equil_kernel, dim3(256), dim3(BLK), 0, stream,
                       pos0, tip, thetas, buckle, ks, ko, kr, out);
}

// Round 3
// 49.069 us; speedup vs baseline: 3.6034x; 1.6941x over previous
//
#include <hip/hip_runtime.h>

#define NN 1026   // nodes per chain
#define NE 1025   // edges
#define NA 1024   // angles
#define BLK 1024

// minimax atan2, max err ~2e-6 rad; inputs never both zero here
__device__ __forceinline__ float fast_atan2f(float y, float x) {
    float ax = __builtin_fabsf(x), ay = __builtin_fabsf(y);
    float mx = fmaxf(ax, ay), mn = fminf(ax, ay);
    float a  = mn * __builtin_amdgcn_rcpf(mx);
    float s  = a * a;
    float r  = fmaf(s, -0.0117212f,  0.05265332f);
    r = fmaf(s, r, -0.11643287f);
    r = fmaf(s, r,  0.19354346f);
    r = fmaf(s, r, -0.33262347f);
    r = fmaf(s, r,  0.99997726f);
    r *= a;
    if (ay > ax)  r = 1.57079637f - r;
    if (x < 0.0f) r = 3.14159274f - r;
    return copysignf(r, y);
}

__global__ __launch_bounds__(BLK)
void equil_kernel(const float* __restrict__ pos0,
                  const float* __restrict__ tip_pos,
                  const float* __restrict__ thetas_ss,
                  const int*   __restrict__ buckle,
                  const float* __restrict__ kstiff_p,
                  const float* __restrict__ ksoft_p,
                  const float* __restrict__ kstretch_p,
                  float* __restrict__ out)
{
    __shared__ float2 pos[NN];   // node positions
    __shared__ float2 Ps[NE];    // P_j = S_j + a_j   (a_1024 = 0)
    __shared__ float2 Qs[NA];    // Q_j = S_j + a_j - b_j
    __shared__ float2 Bs[NA];    // b_j

    const int b   = blockIdx.x;
    const int tid = threadIdx.x;
    const float k_str  = kstretch_p[0];
    const float k_sd   = kstiff_p[0] - ksoft_p[0];
    const float k4soft = 4.0f * ksoft_p[0];

    // ---- init ----
    const float2* p0 = (const float2*)(pos0 + (size_t)b * NN * 2);
    pos[tid] = p0[tid];                       // nodes 0..1023
    if (tid == 0) pos[NA] = p0[NA];           // node 1024
    if (tid == 1) {                           // node 1025 = tip (pinned)
        float2 t; t.x = tip_pos[2*b]; t.y = tip_pos[2*b+1];
        pos[NN-1] = t;
    }
    const float TH = thetas_ss[tid];
    const int4 bk  = ((const int4*)buckle)[tid];
    const float npl = (float)(bk.x + bk.y + bk.z + bk.w);   // #(pm==+1)
    float vxr = 0.f, vyr = 0.f;               // velocity of owned node tid+2
    __syncthreads();
    float2 myp = pos[tid + 2];                // owned free node (tid<=1022)

    for (int s = 0; s < 64; ++s) {
        // ---- phase AB: per-angle bend + per-edge stretch (fused) ----
        float2 pa = pos[tid], pb = pos[tid+1], pc = pos[tid+2];
        float v1x = pb.x - pa.x, v1y = pb.y - pa.y;
        float v2x = pc.x - pb.x, v2y = pc.y - pb.y;
        float l2a = fmaf(v1x, v1x, v1y * v1y);
        float l2b = fmaf(v2x, v2x, v2y * v2y);
        float cr  = v1x * v2y - v1y * v2x;
        float dt_ = fmaf(v1x, v2x, v1y * v2y);
        float theta = fast_atan2f(cr, dt_);
        float cnt = (theta <  TH ? npl        : 0.f)
                  + (theta > -TH ? 4.f - npl  : 0.f);
        float K = fmaf(cnt, k_sd, k4soft);
        float m = K * (theta - TH);
        float ila = __builtin_amdgcn_rsqf(l2a);   // 1/len_a
        float ilb = __builtin_amdgcn_rsqf(l2b);   // 1/len_b
        float m1 = m * ila * ila;                 // m / l2a
        float m2 = m * ilb * ilb;                 // m / l2b
        float2 av; av.x =  m1 * v1y;  av.y = -m1 * v1x;
        float2 bv; bv.x = -m2 * v2y;  bv.y =  m2 * v2x;
        float sca = k_str * (1.0f - ila);         // k*(len-1)/len
        float2 P;  P.x = fmaf(sca, v1x, av.x);  P.y = fmaf(sca, v1y, av.y);
        float2 Q;  Q.x = P.x - bv.x;            Q.y = P.y - bv.y;
        Ps[tid] = P;
        Qs[tid] = Q;
        Bs[tid] = bv;
        if (tid == NA - 1) {   // edge 1024 (S only; a_1024=0)
            float scb = k_str * (1.0f - ilb);
            float2 PN; PN.x = scb * v2x; PN.y = scb * v2y;
            Ps[NA] = PN;
        }
        __syncthreads();

        // ---- phase C: f_n = P[n] - Q[n-1] - B[n-2];  n = tid+2 ----
        if (tid <= NN - 4) {   // free nodes 2..1024
            const int i = tid + 2;
            float2 Pn = Ps[i];
            float2 Qm = Qs[i-1];
            float2 Bm = Bs[i-2];
            float fx = Pn.x - Qm.x - Bm.x;
            float fy = Pn.y - Qm.y - Bm.y;
            vxr += 0.001f * (fx - 2.0f * vxr);
            vyr += 0.001f * (fy - 2.0f * vyr);
            myp.x += 0.001f * vxr;
            myp.y += 0.001f * vyr;
            pos[i] = myp;
        }
        __syncthreads();
    }

    // ---- epilogue ----
    float2* o = (float2*)(out + (size_t)b * NN * 2);
    o[tid] = pos[tid];
    if (tid < 2) o[NA + tid] = pos[NA + tid];
}

extern "C" void kernel_launch(void* const* d_in, const int* in_sizes, int n_in,
                              void* d_out, int out_size, void* d_ws, size_t ws_size,
                              hipStream_t stream) {
    const float* pos0   = (const float*)d_in[0];
    const float* tip    = (const float*)d_in[1];
    const float* thetas = (const float*)d_in[2];
    const int*   buckle = (const int*)  d_in[3];
    const float* ks     = (const float*)d_in[4];
    const float* ko     = (const float*)d_in[5];
    const float* kr     = (const float*)d_in[6];
    float* out = (float*)d_out;
    hipLaunchKernelGGL(equil_kernel, dim3(256), dim3(BLK), 0, stream,
                       pos0, tip, thetas, buckle, ks, ko, kr, out);
}